// Round 8
// baseline (333.495 us; speedup 1.0000x reference)
//
#include <hip/hip_runtime.h>
#include <utility>

typedef _Float16 f16x2 __attribute__((ext_vector_type(2)));

// ---- problem constants ----
#define B_NODES 4000
#define C_CH    128
#define E_ELEM  10
#define NT      219   // 9 + 45 + 165 monomials of degree 1..3 in 9 vars
#define NPP     112   // t-pairs padded to 14 chunks of 8
#define CPP     8     // pairs per chunk
#define NCHUNK  14
#define NB      4     // same-element nodes per block
#define BCAP    768   // per-element bucket capacity

// ---- workspace layout ----
#define OFF_A3_0 0        // [165][8]
#define OFF_A3_1 1320     // [3][165][11]
#define OFF_A2_0 6765     // [45][3]
#define OFF_A2_1 6900     // [3][45][4]
#define OFF_A1_0 7440     // [9]
#define OFF_A1_1 7449     // [3][9]
#define A_TOTAL  7476
#define G_BYTES        (E_ELEM * NPP * C_CH * 16)            // 2,293,760
#define OFF_G_BYTES    32768
#define OFF_PERM_BYTES (OFF_G_BYTES + G_BYTES)
#define OFF_CNT_BYTES  (OFF_PERM_BYTES + E_ELEM * BCAP * 4)

#if defined(__has_builtin)
#if __has_builtin(__builtin_amdgcn_fdot2)
#define HAVE_FDOT2 1
#endif
#endif

// ================= compile-time monomial table =================
// GROUPED ordering: t=0..8 deg-1; then per (i,j) lexicographic a contiguous
// group [deg2(i,j), deg3(i,j,p) p=j..8] so base y[i]*y[j] is short-lived.
struct M3 { int i, j, p, deg; };

constexpr M3 mono(int t) {
    if (t < 9) return M3{t, 0, 0, 1};
    int r = t - 9;
    for (int a = 0; a < 9; a++)
        for (int b = a; b < 9; b++) {
            int gs = 1 + (9 - b);
            if (r < gs) {
                if (r == 0) return M3{a, b, 0, 2};
                return M3{a, b, b + r - 1, 3};
            }
            r -= gs;
        }
    return M3{0, 0, 0, 0};   // padding t>=219 -> deg 0
}

template <int T>
__device__ __forceinline__ float phi_t(const float (&y)[9]) {
    constexpr M3 m = mono(T);
    if constexpr (m.deg == 1) return y[m.i];
    else if constexpr (m.deg == 2) return y[m.i] * y[m.j];
    else if constexpr (m.deg == 3) return (y[m.i] * y[m.j]) * y[m.p];
    else return 0.f;
}

// runtime decode of grouped order -> indices + lexicographic A-table indices
__device__ inline void mono_rt(int t, int& i, int& j, int& p, int& deg, int& t2, int& t3) {
    i = j = p = t2 = t3 = 0;
    if (t < 9) { i = t; deg = 1; return; }
    int r = t - 9, q2 = 0, q3 = 0;
    for (int a = 0; a < 9; a++)
        for (int b = a; b < 9; b++) {
            int gs = 1 + (9 - b);
            if (r < gs) {
                i = a; j = b;
                if (r == 0) { deg = 2; t2 = q2; return; }
                p = b + r - 1; deg = 3; t3 = q3 + (r - 1); return;
            }
            r -= gs; q2++; q3 += 9 - b;
        }
    deg = 0;
}

// ================= helpers for precompute kernels =================
__device__ inline void decode3(int t, int& i, int& j, int& p) {
    int idx = 0;
    for (int a = 0; a < 9; a++)
        for (int b = a; b < 9; b++)
            for (int c = b; c < 9; c++) {
                if (idx == t) { i = a; j = b; p = c; return; }
                idx++;
            }
}

__device__ inline void decode2(int t, int& i, int& j) {
    int idx = 0;
    for (int a = 0; a < 9; a++)
        for (int b = a; b < 9; b++) {
            if (idx == t) { i = a; j = b; return; }
            idx++;
        }
}

__device__ inline float sum3(const float* U, int d, int K, int k, int i, int j, int p) {
    auto at = [&](int a, int b, int c) {
        return U[(((d * 9 + a) * 9 + b) * 9 + c) * K + k];
    };
    if (i == j && j == p) return at(i, i, i);
    if (i == j)           return at(i, i, p) + at(i, p, i) + at(p, i, i);
    if (j == p)           return at(i, j, j) + at(j, i, j) + at(j, j, i);
    return at(i, j, p) + at(i, p, j) + at(j, i, p) + at(j, p, i) + at(p, i, j) + at(p, j, i);
}

__device__ inline float sum2(const float* U, int d, int K, int k, int i, int j) {
    auto at = [&](int a, int b) { return U[((d * 9 + a) * 9 + b) * K + k]; };
    return (i == j) ? at(i, i) : (at(i, j) + at(j, i));
}

// ---- kernel 1: symmetrize U into A ----
__global__ void a_build(const float* __restrict__ U3_0, const float* __restrict__ U2_0,
                        const float* __restrict__ U1_0, const float* __restrict__ U3_1,
                        const float* __restrict__ U2_1, const float* __restrict__ U1_1,
                        float* __restrict__ ws) {
    int tid = blockIdx.x * blockDim.x + threadIdx.x;
    if (tid < 1320) {                       // A3_0 [t3][k], d=0, K=8
        int t3 = tid / 8, k = tid % 8;
        int i, j, p; decode3(t3, i, j, p);
        ws[OFF_A3_0 + tid] = sum3(U3_0, 0, 8, k, i, j, p);
    } else if (tid < 1320 + 5445) {         // A3_1 [d][t3][k], K=11
        int r = tid - 1320;
        int d = r / (165 * 11); int r2 = r % (165 * 11);
        int t3 = r2 / 11, k = r2 % 11;
        int i, j, p; decode3(t3, i, j, p);
        ws[OFF_A3_1 + r] = sum3(U3_1, d, 11, k, i, j, p);
    } else if (tid < 6765 + 135) {          // A2_0 [t2][k], K=3
        int r = tid - 6765;
        int t2 = r / 3, k = r % 3;
        int i, j; decode2(t2, i, j);
        ws[OFF_A2_0 + r] = sum2(U2_0, 0, 3, k, i, j);
    } else if (tid < 6900 + 540) {          // A2_1 [d][t2][k], K=4
        int r = tid - 6900;
        int d = r / 180; int t2 = (r % 180) / 4; int k = r % 4;
        int i, j; decode2(t2, i, j);
        ws[OFF_A2_1 + r] = sum2(U2_1, d, 4, k, i, j);
    } else if (tid < 7440 + 9) {            // A1_0 [i]
        int i = tid - 7440;
        ws[OFF_A1_0 + i] = U1_0[i];
    } else if (tid < 7449 + 27) {           // A1_1 [d][i]
        int r = tid - 7449;
        ws[OFF_A1_1 + r] = U1_1[r];
    }
}

// ---- kernel 2: fuse weights into G[e][tp][c] = uint4 of 4x half2 ----
__device__ void compute_g(int t, int e, int c, const float* __restrict__ ws,
                          const float* __restrict__ W3_0, const float* __restrict__ W2_0,
                          const float* __restrict__ W1_0, const float* __restrict__ W3_1,
                          const float* __restrict__ W2_1, const float* __restrict__ W1_1,
                          float g[4]) {
    if (t >= NT) { g[0] = g[1] = g[2] = g[3] = 0.f; return; }
    int i, j, p, deg, t2, t3;
    mono_rt(t, i, j, p, deg, t2, t3);
    if (deg == 1) {
        float w0 = W1_0[e * C_CH + c];
        float w1 = W1_1[e * C_CH + c];
        g[0] = ws[OFF_A1_0 + i] * w0;
        for (int d = 0; d < 3; d++) g[1 + d] = ws[OFF_A1_1 + d * 9 + i] * w1;
    } else if (deg == 2) {
        float s = 0.f;
        for (int k = 0; k < 3; k++) s += ws[OFF_A2_0 + t2 * 3 + k] * W2_0[(e * 3 + k) * C_CH + c];
        g[0] = s;
        for (int d = 0; d < 3; d++) {
            s = 0.f;
            for (int k = 0; k < 4; k++) s += ws[OFF_A2_1 + (d * 45 + t2) * 4 + k] * W2_1[(e * 4 + k) * C_CH + c];
            g[1 + d] = s;
        }
    } else {
        float s = 0.f;
        for (int k = 0; k < 8; k++) s += ws[OFF_A3_0 + t3 * 8 + k] * W3_0[(e * 8 + k) * C_CH + c];
        g[0] = s;
        for (int d = 0; d < 3; d++) {
            s = 0.f;
            for (int k = 0; k < 11; k++) s += ws[OFF_A3_1 + (d * 165 + t3) * 11 + k] * W3_1[(e * 11 + k) * C_CH + c];
            g[1 + d] = s;
        }
    }
}

__device__ inline unsigned pack_h2(float a, float b) {
    unsigned short ha = __builtin_bit_cast(unsigned short, (_Float16)a);
    unsigned short hb = __builtin_bit_cast(unsigned short, (_Float16)b);
    return (unsigned)ha | ((unsigned)hb << 16);
}

__global__ void g_build(const float* __restrict__ W3_0, const float* __restrict__ W2_0,
                        const float* __restrict__ W1_0, const float* __restrict__ W3_1,
                        const float* __restrict__ W2_1, const float* __restrict__ W1_1,
                        const float* __restrict__ ws, uint4* __restrict__ G) {
    int tid = blockIdx.x * blockDim.x + threadIdx.x;
    if (tid >= E_ELEM * NPP * C_CH) return;
    int c = tid & (C_CH - 1);
    int r = tid >> 7;          // r = e*NPP + tp
    int tp = r % NPP;
    int e = r / NPP;

    float ga[4], gb[4];
    compute_g(2 * tp,     e, c, ws, W3_0, W2_0, W1_0, W3_1, W2_1, W1_1, ga);
    compute_g(2 * tp + 1, e, c, ws, W3_0, W2_0, W1_0, W3_1, W2_1, W1_1, gb);

    uint4 u;
    u.x = pack_h2(ga[0], gb[0]);
    u.y = pack_h2(ga[1], gb[1]);
    u.z = pack_h2(ga[2], gb[2]);
    u.w = pack_h2(ga[3], gb[3]);
    G[tid] = u;                // layout: (e*NPP + tp)*C_CH + c
}

// ---- kernel 3: deterministic stable counting sort of nodes by element ----
__global__ void __launch_bounds__(1024) bucket_build(const float* __restrict__ attrs,
                                                     int* __restrict__ perm,
                                                     int* __restrict__ cnt) {
    const int tid = threadIdx.x;
    const int lane = tid & 63, wv = tid >> 6;   // 16 waves
    __shared__ int wsums[16];

    int e_of[4];
#pragma unroll
    for (int q = 0; q < 4; q++) {
        int b = tid * 4 + q;
        int e = -1;
        if (b < B_NODES) {
            e = 0;
            for (int t = 0; t < E_ELEM; t++) e += (attrs[b * E_ELEM + t] > 0.5f) ? t : 0;
        }
        e_of[q] = e;
    }

    for (int e = 0; e < E_ELEM; e++) {
        int v = 0;
#pragma unroll
        for (int q = 0; q < 4; q++) v += (e_of[q] == e) ? 1 : 0;
        int s = v;
        for (int off = 1; off < 64; off <<= 1) {
            int t = __shfl_up(s, off, 64);
            if (lane >= off) s += t;
        }
        if (lane == 63) wsums[wv] = s;
        __syncthreads();
        int wbase = 0, total = 0;
        for (int w = 0; w < 16; w++) {
            int ws_ = wsums[w];
            if (w < wv) wbase += ws_;
            total += ws_;
        }
        int pos = wbase + (s - v);
#pragma unroll
        for (int q = 0; q < 4; q++) {
            if (e_of[q] == e) {
                if (pos < BCAP) perm[e * BCAP + pos] = tid * 4 + q;
                pos++;
            }
        }
        if (tid == 0) cnt[e] = (total < BCAP) ? total : BCAP;
        __syncthreads();
    }
}

// ================= kernel 4: main =================
__device__ __forceinline__ float dot2acc(unsigned w, f16x2 p, float acc) {
#ifdef HAVE_FDOT2
    return __builtin_amdgcn_fdot2(__builtin_bit_cast(f16x2, w), p, acc, false);
#else
    f16x2 h = __builtin_bit_cast(f16x2, w);
    return fmaf((float)p.x, (float)h.x, fmaf((float)p.y, (float)h.y, acc));
#endif
}

__device__ __forceinline__ f16x2 pack_pair(float a, float b) {
    return __builtin_bit_cast(f16x2, __builtin_amdgcn_cvt_pkrtz(a, b));
}

// issue 8 global->LDS DMA (16B/lane) for one chunk; wave wv covers its half
__device__ __forceinline__ void stage_chunk(const char* gsrc_base, char* lds_buf,
                                            int wv, int lane) {
#pragma unroll
    for (int cl = 0; cl < 8; cl++) {
        int call = wv * 8 + cl;
        int q = call * 64 + lane;
        __builtin_amdgcn_global_load_lds(
            (const __attribute__((address_space(1))) unsigned int*)(gsrc_base + (size_t)q * 16),
            (__attribute__((address_space(3))) unsigned int*)(lds_buf + call * 1024),
            16, 0, 0);
    }
}

template <int TP>
__device__ __forceinline__ void pair_compute(const float (&y)[NB][9], uint4 u,
                                             float (&acc)[NB][4]) {
#pragma unroll
    for (int n = 0; n < NB; n++) {
        float p0 = phi_t<2 * TP>(y[n]);
        float p1 = phi_t<2 * TP + 1>(y[n]);
        f16x2 p = pack_pair(p0, p1);
        acc[n][0] = dot2acc(u.x, p, acc[n][0]);
        acc[n][1] = dot2acc(u.y, p, acc[n][1]);
        acc[n][2] = dot2acc(u.z, p, acc[n][2]);
        acc[n][3] = dot2acc(u.w, p, acc[n][3]);
    }
}

template <int K, std::size_t... R>
__device__ __forceinline__ void chunk_compute(std::index_sequence<R...>,
                                              const float (&y)[NB][9],
                                              const uint4* __restrict__ buf, int c,
                                              float (&acc)[NB][4]) {
    (pair_compute<K * CPP + (int)R>(y, buf[R * C_CH + c], acc), ...);
}

// Opacify y per chunk: empty asm "+v" on every y register creates fresh SSA
// defs each chunk, so monomial products cannot be CSE'd/hoisted across chunks
// (this -- ALU value hoisting, not G-loads -- was the R4-R7 spill source).
__device__ __forceinline__ void opacify_y(float (&y)[NB][9]) {
#pragma unroll
    for (int n = 0; n < NB; n++)
        asm volatile("" : "+v"(y[n][0]), "+v"(y[n][1]), "+v"(y[n][2]),
                          "+v"(y[n][3]), "+v"(y[n][4]), "+v"(y[n][5]),
                          "+v"(y[n][6]), "+v"(y[n][7]), "+v"(y[n][8]));
}

template <int K>
__device__ __forceinline__ void chunk_phase(const char* gsrc, char* smem, int wv, int lane,
                                            float (&y)[NB][9], int c,
                                            float (&acc)[NB][4]) {
    if constexpr (K + 1 < NCHUNK) {
        stage_chunk(gsrc + (size_t)(K + 1) * CPP * C_CH * 16, smem + ((K + 1) & 1) * 16384,
                    wv, lane);
        asm volatile("s_waitcnt vmcnt(8)" ::: "memory");   // chunk K landed; K+1 in flight
    } else {
        asm volatile("s_waitcnt vmcnt(0)" ::: "memory");   // last chunk: drain
    }
    __builtin_amdgcn_s_barrier();                          // all waves' DMA visible
    opacify_y(y);                                          // fence ALU dataflow per chunk
    const uint4* buf = (const uint4*)(smem + (K & 1) * 16384);
    chunk_compute<K>(std::make_index_sequence<CPP>{}, y, buf, c, acc);
    asm volatile("" ::: "memory");
    __builtin_amdgcn_s_barrier();                          // reads done before next overwrite
}

template <std::size_t... K>
__device__ __forceinline__ void run_chunks(std::index_sequence<K...>, const char* gsrc,
                                           char* smem, int wv, int lane,
                                           float (&y)[NB][9], int c,
                                           float (&acc)[NB][4]) {
    (chunk_phase<(int)K>(gsrc, smem, wv, lane, y, c, acc), ...);
}

__global__ void __launch_bounds__(C_CH) sc_main(const float* __restrict__ x,
                                                const int* __restrict__ perm,
                                                const int* __restrict__ cnt,
                                                const uint4* __restrict__ G,
                                                float* __restrict__ out) {
    // 2 x 16KB G double-buffer; x-staging area aliases it (dead before 1st stage)
    __shared__ __align__(16) char smem[2 * 16384];
    const int e = blockIdx.y;
    const int chunk_blk = blockIdx.x;
    const int c = threadIdx.x;
    const int lane = c & 63, wv = c >> 6;

    int cn = cnt[e];
    if (cn > BCAP) cn = BCAP;
    if (chunk_blk * NB >= cn) return;      // block-uniform exit

    int nid[NB];
#pragma unroll
    for (int n = 0; n < NB; n++) {
        int idx = chunk_blk * NB + n;
        nid[n] = (idx < cn) ? perm[e * BCAP + idx] : -1;
    }

    // stage x rows (coalesced float4) into LDS, then extract y (stride-9)
    float* xs = (float*)smem;              // NB*1152 floats = 18,432 B
#pragma unroll
    for (int n = 0; n < NB; n++) {
        float4* dst = reinterpret_cast<float4*>(xs + n * (C_CH * 9));
        if (nid[n] >= 0) {
            const float4* src = reinterpret_cast<const float4*>(x + (size_t)nid[n] * (C_CH * 9));
            dst[c] = src[c];
            dst[c + 128] = src[c + 128];
            if (c < 32) dst[c + 256] = src[c + 256];
        } else {
            float4 z = make_float4(0.f, 0.f, 0.f, 0.f);
            dst[c] = z;
            dst[c + 128] = z;
            if (c < 32) dst[c + 256] = z;
        }
    }
    __syncthreads();

    float y[NB][9];
#pragma unroll
    for (int n = 0; n < NB; n++)
#pragma unroll
        for (int i = 0; i < 9; i++) y[n][i] = xs[n * (C_CH * 9) + c * 9 + i];
    __syncthreads();                       // xs dead; safe to overwrite with G chunks

    float acc[NB][4];
#pragma unroll
    for (int n = 0; n < NB; n++)
#pragma unroll
        for (int d = 0; d < 4; d++) acc[n][d] = 0.f;

    const char* gsrc = (const char*)(G + (size_t)e * NPP * C_CH);   // element's table
    stage_chunk(gsrc, smem, wv, lane);     // prologue: chunk 0 -> buf0

    run_chunks(std::make_index_sequence<NCHUNK>{}, gsrc, smem, wv, lane, y, c, acc);

#pragma unroll
    for (int n = 0; n < NB; n++) {
        if (nid[n] >= 0) {
            int ob = nid[n] * 512;
            out[ob + c] = acc[n][0];
            int o1 = ob + 128 + 3 * c;
            out[o1 + 0] = acc[n][1];
            out[o1 + 1] = acc[n][2];
            out[o1 + 2] = acc[n][3];
        }
    }
}

extern "C" void kernel_launch(void* const* d_in, const int* in_sizes, int n_in,
                              void* d_out, int out_size, void* d_ws, size_t ws_size,
                              hipStream_t stream) {
    const float* x     = (const float*)d_in[0];
    const float* attrs = (const float*)d_in[1];
    const float* U3_0  = (const float*)d_in[2];
    const float* U2_0  = (const float*)d_in[3];
    const float* U1_0  = (const float*)d_in[4];
    const float* W3_0  = (const float*)d_in[5];
    const float* W2_0  = (const float*)d_in[6];
    const float* W1_0  = (const float*)d_in[7];
    const float* U3_1  = (const float*)d_in[8];
    const float* U2_1  = (const float*)d_in[9];
    const float* U1_1  = (const float*)d_in[10];
    const float* W3_1  = (const float*)d_in[11];
    const float* W2_1  = (const float*)d_in[12];
    const float* W1_1  = (const float*)d_in[13];

    float* wsA = (float*)d_ws;
    uint4* G   = (uint4*)((char*)d_ws + OFF_G_BYTES);
    int* perm  = (int*)((char*)d_ws + OFF_PERM_BYTES);
    int* cnt   = (int*)((char*)d_ws + OFF_CNT_BYTES);

    bucket_build<<<1, 1024, 0, stream>>>(attrs, perm, cnt);

    a_build<<<(A_TOTAL + 255) / 256, 256, 0, stream>>>(U3_0, U2_0, U1_0, U3_1, U2_1, U1_1, wsA);

    int ng = E_ELEM * NPP * C_CH;
    g_build<<<(ng + 255) / 256, 256, 0, stream>>>(W3_0, W2_0, W1_0, W3_1, W2_1, W1_1, wsA, G);

    dim3 grid(BCAP / NB, E_ELEM);
    sc_main<<<grid, C_CH, 0, stream>>>(x, perm, cnt, G, (float*)d_out);
}

// Round 9
// 221.913 us; speedup vs baseline: 1.5028x; 1.5028x over previous
//
#include <hip/hip_runtime.h>
#include <utility>

typedef _Float16 f16x2 __attribute__((ext_vector_type(2)));

// ---- problem constants ----
#define B_NODES 4000
#define C_CH    128
#define E_ELEM  10
#define NT      219   // 9 + 45 + 165 monomials of degree 1..3 in 9 vars
#define NPP     112   // t-pairs padded to 14 chunks of 8
#define CPP     8     // pairs per chunk
#define NCHUNK  14
#define NB      4     // same-element nodes per block (one 128-thread group each)
#define BCAP    768   // per-element bucket capacity

// ---- workspace layout ----
#define OFF_A3_0 0        // [165][8]
#define OFF_A3_1 1320     // [3][165][11]
#define OFF_A2_0 6765     // [45][3]
#define OFF_A2_1 6900     // [3][45][4]
#define OFF_A1_0 7440     // [9]
#define OFF_A1_1 7449     // [3][9]
#define A_TOTAL  7476
#define G_BYTES        (E_ELEM * NPP * C_CH * 16)            // 2,293,760
#define OFF_G_BYTES    32768
#define OFF_PERM_BYTES (OFF_G_BYTES + G_BYTES)
#define OFF_CNT_BYTES  (OFF_PERM_BYTES + E_ELEM * BCAP * 4)

#if defined(__has_builtin)
#if __has_builtin(__builtin_amdgcn_fdot2)
#define HAVE_FDOT2 1
#endif
#endif

// ================= compile-time monomial table =================
// GROUPED ordering: t=0..8 deg-1; then per (i,j) lexicographic a contiguous
// group [deg2(i,j), deg3(i,j,p) p=j..8].
struct M3 { int i, j, p, deg; };

constexpr M3 mono(int t) {
    if (t < 9) return M3{t, 0, 0, 1};
    int r = t - 9;
    for (int a = 0; a < 9; a++)
        for (int b = a; b < 9; b++) {
            int gs = 1 + (9 - b);
            if (r < gs) {
                if (r == 0) return M3{a, b, 0, 2};
                return M3{a, b, b + r - 1, 3};
            }
            r -= gs;
        }
    return M3{0, 0, 0, 0};   // padding t>=219 -> deg 0
}

template <int T>
__device__ __forceinline__ float phi_t(const float (&y)[9]) {
    constexpr M3 m = mono(T);
    if constexpr (m.deg == 1) return y[m.i];
    else if constexpr (m.deg == 2) return y[m.i] * y[m.j];
    else if constexpr (m.deg == 3) return (y[m.i] * y[m.j]) * y[m.p];
    else return 0.f;
}

// runtime decode of grouped order -> indices + lexicographic A-table indices
__device__ inline void mono_rt(int t, int& i, int& j, int& p, int& deg, int& t2, int& t3) {
    i = j = p = t2 = t3 = 0;
    if (t < 9) { i = t; deg = 1; return; }
    int r = t - 9, q2 = 0, q3 = 0;
    for (int a = 0; a < 9; a++)
        for (int b = a; b < 9; b++) {
            int gs = 1 + (9 - b);
            if (r < gs) {
                i = a; j = b;
                if (r == 0) { deg = 2; t2 = q2; return; }
                p = b + r - 1; deg = 3; t3 = q3 + (r - 1); return;
            }
            r -= gs; q2++; q3 += 9 - b;
        }
    deg = 0;
}

// ================= helpers for precompute kernels =================
__device__ inline void decode3(int t, int& i, int& j, int& p) {
    int idx = 0;
    for (int a = 0; a < 9; a++)
        for (int b = a; b < 9; b++)
            for (int c = b; c < 9; c++) {
                if (idx == t) { i = a; j = b; p = c; return; }
                idx++;
            }
}

__device__ inline void decode2(int t, int& i, int& j) {
    int idx = 0;
    for (int a = 0; a < 9; a++)
        for (int b = a; b < 9; b++) {
            if (idx == t) { i = a; j = b; return; }
            idx++;
        }
}

__device__ inline float sum3(const float* U, int d, int K, int k, int i, int j, int p) {
    auto at = [&](int a, int b, int c) {
        return U[(((d * 9 + a) * 9 + b) * 9 + c) * K + k];
    };
    if (i == j && j == p) return at(i, i, i);
    if (i == j)           return at(i, i, p) + at(i, p, i) + at(p, i, i);
    if (j == p)           return at(i, j, j) + at(j, i, j) + at(j, j, i);
    return at(i, j, p) + at(i, p, j) + at(j, i, p) + at(j, p, i) + at(p, i, j) + at(p, j, i);
}

__device__ inline float sum2(const float* U, int d, int K, int k, int i, int j) {
    auto at = [&](int a, int b) { return U[((d * 9 + a) * 9 + b) * K + k]; };
    return (i == j) ? at(i, i) : (at(i, j) + at(j, i));
}

// ---- kernel 1: symmetrize U into A ----
__global__ void a_build(const float* __restrict__ U3_0, const float* __restrict__ U2_0,
                        const float* __restrict__ U1_0, const float* __restrict__ U3_1,
                        const float* __restrict__ U2_1, const float* __restrict__ U1_1,
                        float* __restrict__ ws) {
    int tid = blockIdx.x * blockDim.x + threadIdx.x;
    if (tid < 1320) {                       // A3_0 [t3][k], d=0, K=8
        int t3 = tid / 8, k = tid % 8;
        int i, j, p; decode3(t3, i, j, p);
        ws[OFF_A3_0 + tid] = sum3(U3_0, 0, 8, k, i, j, p);
    } else if (tid < 1320 + 5445) {         // A3_1 [d][t3][k], K=11
        int r = tid - 1320;
        int d = r / (165 * 11); int r2 = r % (165 * 11);
        int t3 = r2 / 11, k = r2 % 11;
        int i, j, p; decode3(t3, i, j, p);
        ws[OFF_A3_1 + r] = sum3(U3_1, d, 11, k, i, j, p);
    } else if (tid < 6765 + 135) {          // A2_0 [t2][k], K=3
        int r = tid - 6765;
        int t2 = r / 3, k = r % 3;
        int i, j; decode2(t2, i, j);
        ws[OFF_A2_0 + r] = sum2(U2_0, 0, 3, k, i, j);
    } else if (tid < 6900 + 540) {          // A2_1 [d][t2][k], K=4
        int r = tid - 6900;
        int d = r / 180; int t2 = (r % 180) / 4; int k = r % 4;
        int i, j; decode2(t2, i, j);
        ws[OFF_A2_1 + r] = sum2(U2_1, d, 4, k, i, j);
    } else if (tid < 7440 + 9) {            // A1_0 [i]
        int i = tid - 7440;
        ws[OFF_A1_0 + i] = U1_0[i];
    } else if (tid < 7449 + 27) {           // A1_1 [d][i]
        int r = tid - 7449;
        ws[OFF_A1_1 + r] = U1_1[r];
    }
}

// ---- kernel 2: fuse weights into G[e][tp][c] = uint4 of 4x half2 ----
__device__ void compute_g(int t, int e, int c, const float* __restrict__ ws,
                          const float* __restrict__ W3_0, const float* __restrict__ W2_0,
                          const float* __restrict__ W1_0, const float* __restrict__ W3_1,
                          const float* __restrict__ W2_1, const float* __restrict__ W1_1,
                          float g[4]) {
    if (t >= NT) { g[0] = g[1] = g[2] = g[3] = 0.f; return; }
    int i, j, p, deg, t2, t3;
    mono_rt(t, i, j, p, deg, t2, t3);
    if (deg == 1) {
        float w0 = W1_0[e * C_CH + c];
        float w1 = W1_1[e * C_CH + c];
        g[0] = ws[OFF_A1_0 + i] * w0;
        for (int d = 0; d < 3; d++) g[1 + d] = ws[OFF_A1_1 + d * 9 + i] * w1;
    } else if (deg == 2) {
        float s = 0.f;
        for (int k = 0; k < 3; k++) s += ws[OFF_A2_0 + t2 * 3 + k] * W2_0[(e * 3 + k) * C_CH + c];
        g[0] = s;
        for (int d = 0; d < 3; d++) {
            s = 0.f;
            for (int k = 0; k < 4; k++) s += ws[OFF_A2_1 + (d * 45 + t2) * 4 + k] * W2_1[(e * 4 + k) * C_CH + c];
            g[1 + d] = s;
        }
    } else {
        float s = 0.f;
        for (int k = 0; k < 8; k++) s += ws[OFF_A3_0 + t3 * 8 + k] * W3_0[(e * 8 + k) * C_CH + c];
        g[0] = s;
        for (int d = 0; d < 3; d++) {
            s = 0.f;
            for (int k = 0; k < 11; k++) s += ws[OFF_A3_1 + (d * 165 + t3) * 11 + k] * W3_1[(e * 11 + k) * C_CH + c];
            g[1 + d] = s;
        }
    }
}

__device__ inline unsigned pack_h2(float a, float b) {
    unsigned short ha = __builtin_bit_cast(unsigned short, (_Float16)a);
    unsigned short hb = __builtin_bit_cast(unsigned short, (_Float16)b);
    return (unsigned)ha | ((unsigned)hb << 16);
}

__global__ void g_build(const float* __restrict__ W3_0, const float* __restrict__ W2_0,
                        const float* __restrict__ W1_0, const float* __restrict__ W3_1,
                        const float* __restrict__ W2_1, const float* __restrict__ W1_1,
                        const float* __restrict__ ws, uint4* __restrict__ G) {
    int tid = blockIdx.x * blockDim.x + threadIdx.x;
    if (tid >= E_ELEM * NPP * C_CH) return;
    int c = tid & (C_CH - 1);
    int r = tid >> 7;          // r = e*NPP + tp
    int tp = r % NPP;
    int e = r / NPP;

    float ga[4], gb[4];
    compute_g(2 * tp,     e, c, ws, W3_0, W2_0, W1_0, W3_1, W2_1, W1_1, ga);
    compute_g(2 * tp + 1, e, c, ws, W3_0, W2_0, W1_0, W3_1, W2_1, W1_1, gb);

    uint4 u;
    u.x = pack_h2(ga[0], gb[0]);
    u.y = pack_h2(ga[1], gb[1]);
    u.z = pack_h2(ga[2], gb[2]);
    u.w = pack_h2(ga[3], gb[3]);
    G[tid] = u;                // layout: (e*NPP + tp)*C_CH + c
}

// ---- kernel 3: deterministic stable counting sort of nodes by element ----
__global__ void __launch_bounds__(1024) bucket_build(const float* __restrict__ attrs,
                                                     int* __restrict__ perm,
                                                     int* __restrict__ cnt) {
    const int tid = threadIdx.x;
    const int lane = tid & 63, wv = tid >> 6;   // 16 waves
    __shared__ int wsums[16];

    int e_of[4];
#pragma unroll
    for (int q = 0; q < 4; q++) {
        int b = tid * 4 + q;
        int e = -1;
        if (b < B_NODES) {
            e = 0;
            for (int t = 0; t < E_ELEM; t++) e += (attrs[b * E_ELEM + t] > 0.5f) ? t : 0;
        }
        e_of[q] = e;
    }

    for (int e = 0; e < E_ELEM; e++) {
        int v = 0;
#pragma unroll
        for (int q = 0; q < 4; q++) v += (e_of[q] == e) ? 1 : 0;
        int s = v;
        for (int off = 1; off < 64; off <<= 1) {
            int t = __shfl_up(s, off, 64);
            if (lane >= off) s += t;
        }
        if (lane == 63) wsums[wv] = s;
        __syncthreads();
        int wbase = 0, total = 0;
        for (int w = 0; w < 16; w++) {
            int ws_ = wsums[w];
            if (w < wv) wbase += ws_;
            total += ws_;
        }
        int pos = wbase + (s - v);
#pragma unroll
        for (int q = 0; q < 4; q++) {
            if (e_of[q] == e) {
                if (pos < BCAP) perm[e * BCAP + pos] = tid * 4 + q;
                pos++;
            }
        }
        if (tid == 0) cnt[e] = (total < BCAP) ? total : BCAP;
        __syncthreads();
    }
}

// ================= kernel 4: main =================
// 512 threads = NB(4) node-groups x 128 channels. Each thread owns exactly one
// (node, channel): per-thread state is R2's proven spill-free 1-node dataflow
// (y[9] + acc[4], VGPR~32-64). The 4 groups SHARE each staged G chunk in LDS.
__device__ __forceinline__ float dot2acc(unsigned w, f16x2 p, float acc) {
#ifdef HAVE_FDOT2
    return __builtin_amdgcn_fdot2(__builtin_bit_cast(f16x2, w), p, acc, false);
#else
    f16x2 h = __builtin_bit_cast(f16x2, w);
    return fmaf((float)p.x, (float)h.x, fmaf((float)p.y, (float)h.y, acc));
#endif
}

__device__ __forceinline__ f16x2 pack_pair(float a, float b) {
    return __builtin_bit_cast(f16x2, __builtin_amdgcn_cvt_pkrtz(a, b));
}

// 8 waves x 2 DMA (16B/lane) = 16KB chunk -> LDS
__device__ __forceinline__ void stage_chunk(const char* gsrc_base, char* lds_buf,
                                            int wv, int lane) {
#pragma unroll
    for (int cl = 0; cl < 2; cl++) {
        int call = wv * 2 + cl;                 // 0..15 kilobyte-slot
        int q = call * 64 + lane;
        __builtin_amdgcn_global_load_lds(
            (const __attribute__((address_space(1))) unsigned int*)(gsrc_base + (size_t)q * 16),
            (__attribute__((address_space(3))) unsigned int*)(lds_buf + call * 1024),
            16, 0, 0);
    }
}

template <int TP>
__device__ __forceinline__ void pair_compute(const float (&y)[9], uint4 u,
                                             float (&acc)[4]) {
    float p0 = phi_t<2 * TP>(y);
    float p1 = phi_t<2 * TP + 1>(y);
    f16x2 p = pack_pair(p0, p1);
    acc[0] = dot2acc(u.x, p, acc[0]);
    acc[1] = dot2acc(u.y, p, acc[1]);
    acc[2] = dot2acc(u.z, p, acc[2]);
    acc[3] = dot2acc(u.w, p, acc[3]);
}

template <int K, std::size_t... R>
__device__ __forceinline__ void chunk_compute(std::index_sequence<R...>,
                                              const float (&y)[9],
                                              const uint4* __restrict__ buf, int c,
                                              float (&acc)[4]) {
    (pair_compute<K * CPP + (int)R>(y, buf[R * C_CH + c], acc), ...);
}

template <int K>
__device__ __forceinline__ void chunk_phase(const char* gsrc, char* smem, int wv, int lane,
                                            const float (&y)[9], int c,
                                            float (&acc)[4]) {
    if constexpr (K + 1 < NCHUNK) {
        stage_chunk(gsrc + (size_t)(K + 1) * 16384, smem + ((K + 1) & 1) * 16384, wv, lane);
        asm volatile("s_waitcnt vmcnt(2)" ::: "memory");   // this wave's chunk-K DMA landed
    } else {
        asm volatile("s_waitcnt vmcnt(0)" ::: "memory");
    }
    __builtin_amdgcn_s_barrier();                          // all waves' chunk-K DMA landed
    asm volatile("" ::: "memory");
    const uint4* buf = (const uint4*)(smem + (K & 1) * 16384);
    chunk_compute<K>(std::make_index_sequence<CPP>{}, y, buf, c, acc);
    asm volatile("" ::: "memory");
    __builtin_amdgcn_s_barrier();                          // reads done before overwrite
}

template <std::size_t... K>
__device__ __forceinline__ void run_chunks(std::index_sequence<K...>, const char* gsrc,
                                           char* smem, int wv, int lane,
                                           const float (&y)[9], int c,
                                           float (&acc)[4]) {
    (chunk_phase<(int)K>(gsrc, smem, wv, lane, y, c, acc), ...);
}

__global__ void __launch_bounds__(512) sc_main(const float* __restrict__ x,
                                               const int* __restrict__ perm,
                                               const int* __restrict__ cnt,
                                               const uint4* __restrict__ G,
                                               float* __restrict__ out) {
    __shared__ __align__(16) char smem[2 * 16384];   // G double buffer only
    const int e = blockIdx.y;
    const int blk = blockIdx.x;
    const int tid = threadIdx.x;
    const int c = tid & (C_CH - 1);
    const int n = tid >> 7;                  // node-group 0..3 (wave-uniform)
    const int lane = tid & 63, wv = tid >> 6;

    int cn = cnt[e];
    if (cn > BCAP) cn = BCAP;
    if (blk * NB >= cn) return;              // block-uniform exit (before any barrier)

    int idx = blk * NB + n;
    int nid = (idx < cn) ? perm[e * BCAP + idx] : -1;   // wave-uniform validity

    float y[9];
    if (nid >= 0) {
        const float* xr = x + (size_t)nid * (C_CH * 9) + c * 9;
#pragma unroll
        for (int i = 0; i < 9; i++) y[i] = xr[i];
    } else {
#pragma unroll
        for (int i = 0; i < 9; i++) y[i] = 0.f;
    }
    // drain all prior global loads so manual vmcnt counts below are exact
    asm volatile("s_waitcnt vmcnt(0)" ::: "memory");

    float acc[4] = {0.f, 0.f, 0.f, 0.f};

    const char* gsrc = (const char*)(G + (size_t)e * NPP * C_CH);
    stage_chunk(gsrc, smem, wv, lane);       // prologue: chunk 0 -> buf0

    run_chunks(std::make_index_sequence<NCHUNK>{}, gsrc, smem, wv, lane, y, c, acc);

    if (nid >= 0) {
        int ob = nid * 512;
        out[ob + c] = acc[0];
        int o1 = ob + 128 + 3 * c;
        out[o1 + 0] = acc[1];
        out[o1 + 1] = acc[2];
        out[o1 + 2] = acc[3];
    }
}

extern "C" void kernel_launch(void* const* d_in, const int* in_sizes, int n_in,
                              void* d_out, int out_size, void* d_ws, size_t ws_size,
                              hipStream_t stream) {
    const float* x     = (const float*)d_in[0];
    const float* attrs = (const float*)d_in[1];
    const float* U3_0  = (const float*)d_in[2];
    const float* U2_0  = (const float*)d_in[3];
    const float* U1_0  = (const float*)d_in[4];
    const float* W3_0  = (const float*)d_in[5];
    const float* W2_0  = (const float*)d_in[6];
    const float* W1_0  = (const float*)d_in[7];
    const float* U3_1  = (const float*)d_in[8];
    const float* U2_1  = (const float*)d_in[9];
    const float* U1_1  = (const float*)d_in[10];
    const float* W3_1  = (const float*)d_in[11];
    const float* W2_1  = (const float*)d_in[12];
    const float* W1_1  = (const float*)d_in[13];

    float* wsA = (float*)d_ws;
    uint4* G   = (uint4*)((char*)d_ws + OFF_G_BYTES);
    int* perm  = (int*)((char*)d_ws + OFF_PERM_BYTES);
    int* cnt   = (int*)((char*)d_ws + OFF_CNT_BYTES);

    bucket_build<<<1, 1024, 0, stream>>>(attrs, perm, cnt);

    a_build<<<(A_TOTAL + 255) / 256, 256, 0, stream>>>(U3_0, U2_0, U1_0, U3_1, U2_1, U1_1, wsA);

    int ng = E_ELEM * NPP * C_CH;
    g_build<<<(ng + 255) / 256, 256, 0, stream>>>(W3_0, W2_0, W1_0, W3_1, W2_1, W1_1, wsA, G);

    dim3 grid(BCAP / NB, E_ELEM);
    sc_main<<<grid, 512, 0, stream>>>(x, perm, cnt, G, (float*)d_out);
}

// Round 10
// 81.033 us; speedup vs baseline: 4.1155x; 2.7386x over previous
//
#include <hip/hip_runtime.h>
#include <utility>

typedef _Float16 f16x2 __attribute__((ext_vector_type(2)));

// ---- problem constants ----
#define B_NODES 4000
#define C_CH    128
#define E_ELEM  10
#define NT      219   // 9 + 45 + 165 monomials of degree 1..3 in 9 vars
#define NPP     112   // t-pairs (padded; tail pairs have zero G)
#define NB_THR  256   // nodes per block (one per thread)
#define BCAP    768   // per-element bucket capacity (3 chunks of 256)

// ---- workspace layout ----
#define OFF_A3_0 0        // [165][8]
#define OFF_A3_1 1320     // [3][165][11]
#define OFF_A2_0 6765     // [45][3]
#define OFF_A2_1 6900     // [3][45][4]
#define OFF_A1_0 7440     // [9]
#define OFF_A1_1 7449     // [3][9]
#define A_TOTAL  7476
#define G_BYTES        (E_ELEM * NPP * C_CH * 16)            // 2,293,760
#define OFF_G_BYTES    32768
#define OFF_PERM_BYTES (OFF_G_BYTES + G_BYTES)
#define OFF_CNT_BYTES  (OFF_PERM_BYTES + E_ELEM * BCAP * 4)

#if defined(__has_builtin)
#if __has_builtin(__builtin_amdgcn_fdot2)
#define HAVE_FDOT2 1
#endif
#endif

// ================= compile-time monomial table =================
// GROUPED ordering: t=0..8 deg-1; then per (i,j) lexicographic a contiguous
// group [deg2(i,j), deg3(i,j,p) p=j..8] so base y[i]*y[j] is short-lived.
struct M3 { int i, j, p, deg; };

constexpr M3 mono(int t) {
    if (t < 9) return M3{t, 0, 0, 1};
    int r = t - 9;
    for (int a = 0; a < 9; a++)
        for (int b = a; b < 9; b++) {
            int gs = 1 + (9 - b);
            if (r < gs) {
                if (r == 0) return M3{a, b, 0, 2};
                return M3{a, b, b + r - 1, 3};
            }
            r -= gs;
        }
    return M3{0, 0, 0, 0};   // padding t>=219 -> deg 0
}

template <int T>
__device__ __forceinline__ float phi_t(const float (&y)[9]) {
    constexpr M3 m = mono(T);
    if constexpr (m.deg == 1) return y[m.i];
    else if constexpr (m.deg == 2) return y[m.i] * y[m.j];
    else if constexpr (m.deg == 3) return (y[m.i] * y[m.j]) * y[m.p];
    else return 0.f;
}

// runtime decode of grouped order -> indices + lexicographic A-table indices
__device__ inline void mono_rt(int t, int& i, int& j, int& p, int& deg, int& t2, int& t3) {
    i = j = p = t2 = t3 = 0;
    if (t < 9) { i = t; deg = 1; return; }
    int r = t - 9, q2 = 0, q3 = 0;
    for (int a = 0; a < 9; a++)
        for (int b = a; b < 9; b++) {
            int gs = 1 + (9 - b);
            if (r < gs) {
                i = a; j = b;
                if (r == 0) { deg = 2; t2 = q2; return; }
                p = b + r - 1; deg = 3; t3 = q3 + (r - 1); return;
            }
            r -= gs; q2++; q3 += 9 - b;
        }
    deg = 0;
}

// ================= helpers for precompute kernels =================
__device__ inline void decode3(int t, int& i, int& j, int& p) {
    int idx = 0;
    for (int a = 0; a < 9; a++)
        for (int b = a; b < 9; b++)
            for (int c = b; c < 9; c++) {
                if (idx == t) { i = a; j = b; p = c; return; }
                idx++;
            }
}

__device__ inline void decode2(int t, int& i, int& j) {
    int idx = 0;
    for (int a = 0; a < 9; a++)
        for (int b = a; b < 9; b++) {
            if (idx == t) { i = a; j = b; return; }
            idx++;
        }
}

__device__ inline float sum3(const float* U, int d, int K, int k, int i, int j, int p) {
    auto at = [&](int a, int b, int c) {
        return U[(((d * 9 + a) * 9 + b) * 9 + c) * K + k];
    };
    if (i == j && j == p) return at(i, i, i);
    if (i == j)           return at(i, i, p) + at(i, p, i) + at(p, i, i);
    if (j == p)           return at(i, j, j) + at(j, i, j) + at(j, j, i);
    return at(i, j, p) + at(i, p, j) + at(j, i, p) + at(j, p, i) + at(p, i, j) + at(p, j, i);
}

__device__ inline float sum2(const float* U, int d, int K, int k, int i, int j) {
    auto at = [&](int a, int b) { return U[((d * 9 + a) * 9 + b) * K + k]; };
    return (i == j) ? at(i, i) : (at(i, j) + at(j, i));
}

// ---- kernel 1: symmetrize U into A ----
__global__ void a_build(const float* __restrict__ U3_0, const float* __restrict__ U2_0,
                        const float* __restrict__ U1_0, const float* __restrict__ U3_1,
                        const float* __restrict__ U2_1, const float* __restrict__ U1_1,
                        float* __restrict__ ws) {
    int tid = blockIdx.x * blockDim.x + threadIdx.x;
    if (tid < 1320) {                       // A3_0 [t3][k], d=0, K=8
        int t3 = tid / 8, k = tid % 8;
        int i, j, p; decode3(t3, i, j, p);
        ws[OFF_A3_0 + tid] = sum3(U3_0, 0, 8, k, i, j, p);
    } else if (tid < 1320 + 5445) {         // A3_1 [d][t3][k], K=11
        int r = tid - 1320;
        int d = r / (165 * 11); int r2 = r % (165 * 11);
        int t3 = r2 / 11, k = r2 % 11;
        int i, j, p; decode3(t3, i, j, p);
        ws[OFF_A3_1 + r] = sum3(U3_1, d, 11, k, i, j, p);
    } else if (tid < 6765 + 135) {          // A2_0 [t2][k], K=3
        int r = tid - 6765;
        int t2 = r / 3, k = r % 3;
        int i, j; decode2(t2, i, j);
        ws[OFF_A2_0 + r] = sum2(U2_0, 0, 3, k, i, j);
    } else if (tid < 6900 + 540) {          // A2_1 [d][t2][k], K=4
        int r = tid - 6900;
        int d = r / 180; int t2 = (r % 180) / 4; int k = r % 4;
        int i, j; decode2(t2, i, j);
        ws[OFF_A2_1 + r] = sum2(U2_1, d, 4, k, i, j);
    } else if (tid < 7440 + 9) {            // A1_0 [i]
        int i = tid - 7440;
        ws[OFF_A1_0 + i] = U1_0[i];
    } else if (tid < 7449 + 27) {           // A1_1 [d][i]
        int r = tid - 7449;
        ws[OFF_A1_1 + r] = U1_1[r];
    }
}

// ---- kernel 2: fuse weights into G[e][tp][c] = uint4 of 4x half2 ----
__device__ void compute_g(int t, int e, int c, const float* __restrict__ ws,
                          const float* __restrict__ W3_0, const float* __restrict__ W2_0,
                          const float* __restrict__ W1_0, const float* __restrict__ W3_1,
                          const float* __restrict__ W2_1, const float* __restrict__ W1_1,
                          float g[4]) {
    if (t >= NT) { g[0] = g[1] = g[2] = g[3] = 0.f; return; }
    int i, j, p, deg, t2, t3;
    mono_rt(t, i, j, p, deg, t2, t3);
    if (deg == 1) {
        float w0 = W1_0[e * C_CH + c];
        float w1 = W1_1[e * C_CH + c];
        g[0] = ws[OFF_A1_0 + i] * w0;
        for (int d = 0; d < 3; d++) g[1 + d] = ws[OFF_A1_1 + d * 9 + i] * w1;
    } else if (deg == 2) {
        float s = 0.f;
        for (int k = 0; k < 3; k++) s += ws[OFF_A2_0 + t2 * 3 + k] * W2_0[(e * 3 + k) * C_CH + c];
        g[0] = s;
        for (int d = 0; d < 3; d++) {
            s = 0.f;
            for (int k = 0; k < 4; k++) s += ws[OFF_A2_1 + (d * 45 + t2) * 4 + k] * W2_1[(e * 4 + k) * C_CH + c];
            g[1 + d] = s;
        }
    } else {
        float s = 0.f;
        for (int k = 0; k < 8; k++) s += ws[OFF_A3_0 + t3 * 8 + k] * W3_0[(e * 8 + k) * C_CH + c];
        g[0] = s;
        for (int d = 0; d < 3; d++) {
            s = 0.f;
            for (int k = 0; k < 11; k++) s += ws[OFF_A3_1 + (d * 165 + t3) * 11 + k] * W3_1[(e * 11 + k) * C_CH + c];
            g[1 + d] = s;
        }
    }
}

__device__ inline unsigned pack_h2(float a, float b) {
    unsigned short ha = __builtin_bit_cast(unsigned short, (_Float16)a);
    unsigned short hb = __builtin_bit_cast(unsigned short, (_Float16)b);
    return (unsigned)ha | ((unsigned)hb << 16);
}

__global__ void g_build(const float* __restrict__ W3_0, const float* __restrict__ W2_0,
                        const float* __restrict__ W1_0, const float* __restrict__ W3_1,
                        const float* __restrict__ W2_1, const float* __restrict__ W1_1,
                        const float* __restrict__ ws, uint4* __restrict__ G) {
    int tid = blockIdx.x * blockDim.x + threadIdx.x;
    if (tid >= E_ELEM * NPP * C_CH) return;
    int c = tid & (C_CH - 1);
    int r = tid >> 7;          // r = e*NPP + tp
    int tp = r % NPP;
    int e = r / NPP;

    float ga[4], gb[4];
    compute_g(2 * tp,     e, c, ws, W3_0, W2_0, W1_0, W3_1, W2_1, W1_1, ga);
    compute_g(2 * tp + 1, e, c, ws, W3_0, W2_0, W1_0, W3_1, W2_1, W1_1, gb);

    uint4 u;
    u.x = pack_h2(ga[0], gb[0]);
    u.y = pack_h2(ga[1], gb[1]);
    u.z = pack_h2(ga[2], gb[2]);
    u.w = pack_h2(ga[3], gb[3]);
    G[tid] = u;                // layout: (e*NPP + tp)*C_CH + c
}

// ---- kernel 3: deterministic stable counting sort of nodes by element ----
__global__ void __launch_bounds__(1024) bucket_build(const float* __restrict__ attrs,
                                                     int* __restrict__ perm,
                                                     int* __restrict__ cnt) {
    const int tid = threadIdx.x;
    const int lane = tid & 63, wv = tid >> 6;   // 16 waves
    __shared__ int wsums[16];

    int e_of[4];
#pragma unroll
    for (int q = 0; q < 4; q++) {
        int b = tid * 4 + q;
        int e = -1;
        if (b < B_NODES) {
            e = 0;
            for (int t = 0; t < E_ELEM; t++) e += (attrs[b * E_ELEM + t] > 0.5f) ? t : 0;
        }
        e_of[q] = e;
    }

    for (int e = 0; e < E_ELEM; e++) {
        int v = 0;
#pragma unroll
        for (int q = 0; q < 4; q++) v += (e_of[q] == e) ? 1 : 0;
        int s = v;
        for (int off = 1; off < 64; off <<= 1) {
            int t = __shfl_up(s, off, 64);
            if (lane >= off) s += t;
        }
        if (lane == 63) wsums[wv] = s;
        __syncthreads();
        int wbase = 0, total = 0;
        for (int w = 0; w < 16; w++) {
            int ws_ = wsums[w];
            if (w < wv) wbase += ws_;
            total += ws_;
        }
        int pos = wbase + (s - v);
#pragma unroll
        for (int q = 0; q < 4; q++) {
            if (e_of[q] == e) {
                if (pos < BCAP) perm[e * BCAP + pos] = tid * 4 + q;
                pos++;
            }
        }
        if (tid == 0) cnt[e] = (total < BCAP) ? total : BCAP;
        __syncthreads();
    }
}

// ================= kernel 4: main =================
// Block = (channel c, element e, node-chunk). 256 threads = 256 same-element
// nodes at ONE fixed c. G[e, tp, c] is block-uniform -> scalar loads (SGPR,
// constant cache); v_dot2 consumes the weight as its single SGPR operand.
// No LDS, no barriers, no DMA. Per-thread state = R2's proven tiny dataflow.
__device__ __forceinline__ float dot2acc(unsigned w, f16x2 p, float acc) {
#ifdef HAVE_FDOT2
    return __builtin_amdgcn_fdot2(__builtin_bit_cast(f16x2, w), p, acc, false);
#else
    f16x2 h = __builtin_bit_cast(f16x2, w);
    return fmaf((float)p.x, (float)h.x, fmaf((float)p.y, (float)h.y, acc));
#endif
}

__device__ __forceinline__ f16x2 pack_pair(float a, float b) {
    return __builtin_bit_cast(f16x2, __builtin_amdgcn_cvt_pkrtz(a, b));
}

template <int TP>
__device__ __forceinline__ void pair_step(const float (&y)[9], const uint4* __restrict__ Gc,
                                          float (&acc)[4]) {
    uint4 u = Gc[TP * C_CH];           // block-uniform address -> s_load
    float p0 = phi_t<2 * TP>(y);
    float p1 = phi_t<2 * TP + 1>(y);
    f16x2 p = pack_pair(p0, p1);
    acc[0] = dot2acc(u.x, p, acc[0]);
    acc[1] = dot2acc(u.y, p, acc[1]);
    acc[2] = dot2acc(u.z, p, acc[2]);
    acc[3] = dot2acc(u.w, p, acc[3]);
}

// bound s_load clustering (SGPR budget ~100): fence every 8 pairs
template <std::size_t I>
__device__ __forceinline__ void maybe_fence() {
    if constexpr ((I % 8) == 7) __builtin_amdgcn_sched_barrier(0);
}

template <std::size_t... I>
__device__ __forceinline__ void run_all(std::index_sequence<I...>, const float (&y)[9],
                                        const uint4* __restrict__ Gc, float (&acc)[4]) {
    ((pair_step<(int)I>(y, Gc, acc), maybe_fence<I>()), ...);
}

__global__ void __launch_bounds__(NB_THR) sc_main(const float* __restrict__ x,
                                                  const int* __restrict__ perm,
                                                  const int* __restrict__ cnt,
                                                  const uint4* __restrict__ G,
                                                  float* __restrict__ out) {
    const int c     = blockIdx.x;          // channel (block-uniform)
    const int chunk = blockIdx.y;          // node chunk
    const int e     = blockIdx.z;          // element
    const int tid   = threadIdx.x;

    int cn = cnt[e];
    if (cn > BCAP) cn = BCAP;
    if (chunk * NB_THR >= cn) return;      // empty chunk

    int idx = chunk * NB_THR + tid;
    bool active = idx < cn;
    int nid = active ? perm[e * BCAP + idx] : 0;

    float y[9];
    if (active) {
        const float* xr = x + ((size_t)nid * C_CH + c) * 9;
#pragma unroll
        for (int i = 0; i < 9; i++) y[i] = xr[i];
    } else {
#pragma unroll
        for (int i = 0; i < 9; i++) y[i] = 0.f;
    }

    float acc[4] = {0.f, 0.f, 0.f, 0.f};
    const uint4* Gc = G + (size_t)e * NPP * C_CH + c;   // uniform base

    run_all(std::make_index_sequence<NPP>{}, y, Gc, acc);

    if (active) {
        int ob = nid * 512;
        out[ob + c] = acc[0];
        int o1 = ob + 128 + 3 * c;
        out[o1 + 0] = acc[1];
        out[o1 + 1] = acc[2];
        out[o1 + 2] = acc[3];
    }
}

extern "C" void kernel_launch(void* const* d_in, const int* in_sizes, int n_in,
                              void* d_out, int out_size, void* d_ws, size_t ws_size,
                              hipStream_t stream) {
    const float* x     = (const float*)d_in[0];
    const float* attrs = (const float*)d_in[1];
    const float* U3_0  = (const float*)d_in[2];
    const float* U2_0  = (const float*)d_in[3];
    const float* U1_0  = (const float*)d_in[4];
    const float* W3_0  = (const float*)d_in[5];
    const float* W2_0  = (const float*)d_in[6];
    const float* W1_0  = (const float*)d_in[7];
    const float* U3_1  = (const float*)d_in[8];
    const float* U2_1  = (const float*)d_in[9];
    const float* U1_1  = (const float*)d_in[10];
    const float* W3_1  = (const float*)d_in[11];
    const float* W2_1  = (const float*)d_in[12];
    const float* W1_1  = (const float*)d_in[13];

    float* wsA = (float*)d_ws;
    uint4* G   = (uint4*)((char*)d_ws + OFF_G_BYTES);
    int* perm  = (int*)((char*)d_ws + OFF_PERM_BYTES);
    int* cnt   = (int*)((char*)d_ws + OFF_CNT_BYTES);

    bucket_build<<<1, 1024, 0, stream>>>(attrs, perm, cnt);

    a_build<<<(A_TOTAL + 255) / 256, 256, 0, stream>>>(U3_0, U2_0, U1_0, U3_1, U2_1, U1_1, wsA);

    int ng = E_ELEM * NPP * C_CH;
    g_build<<<(ng + 255) / 256, 256, 0, stream>>>(W3_0, W2_0, W1_0, W3_1, W2_1, W1_1, wsA, G);

    dim3 grid(C_CH, BCAP / NB_THR, E_ELEM);   // (128, 3, 10)
    sc_main<<<grid, NB_THR, 0, stream>>>(x, perm, cnt, G, (float*)d_out);
}